// Round 1
// baseline (704.759 us; speedup 1.0000x reference)
//
#include <hip/hip_runtime.h>
#include <stdint.h>

// ---------------------------------------------------------------------------
// Problem constants
// ---------------------------------------------------------------------------
#define BB    4096
#define DD    1024
#define TT    768
#define CC    16
#define HH    4
#define SS    4           // sequence length of the stacked gf tensor
#define HD    256         // head dim
#define M1    (BB*SS)     // 16384 rows
#define CURVF 0.05f
#define SCF   0.22360679774997896f   // sqrt(0.05)
#define EPSF  1e-8f
#define ASINH_MAXF 11.090354888959125f  // asinh(2^15)

// d_out element offsets: [logits B*C][loss 1][oh B*D][fh B*D][oeu B*D][feu B*D]
#define OFF_LOGITS 0ull
#define OFF_LOSS   65536ull
#define OFF_OH     65537ull
#define OFF_FH     (65537ull + 4194304ull)
#define OFF_OEU    (65537ull + 2ull*4194304ull)
#define OFF_FEU    (65537ull + 3ull*4194304ull)

// ---------------------------------------------------------------------------
// Helpers
// ---------------------------------------------------------------------------
typedef __attribute__((ext_vector_type(8))) short bf16x8;
typedef __attribute__((ext_vector_type(4))) float f32x4;

__device__ __forceinline__ float bf2f(unsigned short h) {
  union { unsigned int u; float f; } v; v.u = ((unsigned int)h) << 16; return v.f;
}
__device__ __forceinline__ unsigned short f2bf(float f) {
  union { float f; unsigned int u; } v; v.f = f;
  unsigned int u = v.u;
  return (unsigned short)((u + 0x7FFFu + ((u >> 16) & 1u)) >> 16);
}
__device__ __forceinline__ float wsum(float v) {
#pragma unroll
  for (int o = 32; o > 0; o >>= 1) v += __shfl_xor(v, o, 64);
  return v;
}
// 256-thread block sum; `red` is a shared float[4]
__device__ __forceinline__ float block_sum(float v, float* red) {
  v = wsum(v);
  int lane = threadIdx.x & 63, wv = threadIdx.x >> 6;
  __syncthreads();                 // protect red against reuse
  if (lane == 0) red[wv] = v;
  __syncthreads();
  return red[0] + red[1] + red[2] + red[3];
}
__device__ __forceinline__ float artanh_clip(float x) {
  x = fminf(fmaxf(x, -1.0f + 1e-5f), 1.0f - 1e-5f);
  return 0.5f * (log1pf(x) - log1pf(-x));
}

// async global->LDS, 16B per lane (HW: wave-uniform base + lane*16)
typedef __attribute__((address_space(1))) const void gas_void;
typedef __attribute__((address_space(3))) void las_void;
__device__ __forceinline__ void gld16(void* l, const void* g) {
  __builtin_amdgcn_global_load_lds((gas_void*)g, (las_void*)l, 16, 0, 0);
}

// ---------------------------------------------------------------------------
// fp32 -> bf16 convert
// ---------------------------------------------------------------------------
__global__ __launch_bounds__(256) void k_f2bf(const float* __restrict__ in,
                                              unsigned short* __restrict__ out, int n) {
  int i = blockIdx.x * 256 + threadIdx.x;
  if (i < n) out[i] = f2bf(in[i]);
}

__global__ void k_zero(float* p, int n) {
  int i = blockIdx.x * 64 + threadIdx.x;
  if (i < n) p[i] = 0.f;
}

// ---------------------------------------------------------------------------
// gf = stack([p_logmap0(order_hyp), p_logmap0(family_hyp), order_euc, family_euc])
// one block per b; writes bf16 gf (B*4, D)
// ---------------------------------------------------------------------------
__global__ __launch_bounds__(256) void k_prep_gf(const float* __restrict__ ohyp,
    const float* __restrict__ fhyp, const float* __restrict__ oeuc,
    const float* __restrict__ feuc, unsigned short* __restrict__ gf) {
  __shared__ float red[4];
  int b = blockIdx.x;
  size_t base = (size_t)b * DD;
  float xo[4], xf[4], so = 0.f, sf = 0.f;
#pragma unroll
  for (int k = 0; k < 4; k++) {
    int d = threadIdx.x + k * 256;
    xo[k] = ohyp[base + d]; so += xo[k] * xo[k];
    xf[k] = fhyp[base + d]; sf += xf[k] * xf[k];
  }
  float no2 = block_sum(so, red);
  float nf2 = block_sum(sf, red);
  float no = fmaxf(sqrtf(no2), 1e-15f);
  float nf = fmaxf(sqrtf(nf2), 1e-15f);
  float fo = artanh_clip(SCF * no) / (no * SCF);
  float ff = artanh_clip(SCF * nf) / (nf * SCF);
  size_t g0 = (size_t)b * 4 * DD;
#pragma unroll
  for (int k = 0; k < 4; k++) {
    int d = threadIdx.x + k * 256;
    gf[g0 + d]            = f2bf(xo[k] * fo);
    gf[g0 + DD + d]       = f2bf(xf[k] * ff);
    gf[g0 + 2 * DD + d]   = f2bf(oeuc[base + d]);
    gf[g0 + 3 * DD + d]   = f2bf(feuc[base + d]);
  }
}

// ---------------------------------------------------------------------------
// bf16 GEMM, C = A(MxK) * B(NxK)^T + bias  (both row-major, B^T layout)
// 128x128 tile, 4 waves each computing 64x64 via 4x4 x mfma_16x16x32_bf16.
// OUT_BF16: 1 -> write bf16 (ushort), 0 -> write f32.
// ---------------------------------------------------------------------------
template <int OUT_BF16>
__global__ __launch_bounds__(256) void k_gemm_bt(
    const unsigned short* __restrict__ A, const unsigned short* __restrict__ Bm,
    const float* __restrict__ bias, void* __restrict__ Cv, int M, int N, int K) {
  __shared__ unsigned short As[128 * 32];
  __shared__ unsigned short Bs[128 * 32];
  const int tid = threadIdx.x;
  const int lane = tid & 63;
  const int wv = tid >> 6;
  const long tileM = (long)blockIdx.y * 128;
  const long tileN = (long)blockIdx.x * 128;

  f32x4 acc[4][4];
#pragma unroll
  for (int i = 0; i < 4; i++)
#pragma unroll
    for (int j = 0; j < 4; j++) acc[i][j] = (f32x4){0.f, 0.f, 0.f, 0.f};

  // staging: wave w covers rows [w*16, w*16+16) (issue 0) and +64 (issue 1)
  const int srow = wv * 16 + (lane >> 2);
  const int scol = (lane & 3) * 8;
  const unsigned short* Ag = A + (tileM + srow) * (long)K + scol;
  const unsigned short* Bg = Bm + (tileN + srow) * (long)K + scol;
  unsigned short* Asl = As + srow * 32 + scol;   // == base + lane*8 elems
  unsigned short* Bsl = Bs + srow * 32 + scol;

  const int fr = lane & 15;          // fragment row (m or n)
  const int fko = (lane >> 4) * 8;   // fragment k offset
  const int wr = (wv >> 1) * 64;     // wave row offset in tile
  const int wc = (wv & 1) * 64;      // wave col offset in tile

  for (int k0 = 0; k0 < K; k0 += 32) {
    gld16(Asl, Ag + k0);
    gld16(Asl + 64 * 32, Ag + (long)64 * K + k0);
    gld16(Bsl, Bg + k0);
    gld16(Bsl + 64 * 32, Bg + (long)64 * K + k0);
    __syncthreads();   // drains vmcnt for global_load_lds
    bf16x8 af[4], bfr[4];
#pragma unroll
    for (int i = 0; i < 4; i++)
      af[i] = *(const bf16x8*)(As + (wr + i * 16 + fr) * 32 + fko);
#pragma unroll
    for (int j = 0; j < 4; j++)
      bfr[j] = *(const bf16x8*)(Bs + (wc + j * 16 + fr) * 32 + fko);
#pragma unroll
    for (int i = 0; i < 4; i++)
#pragma unroll
      for (int j = 0; j < 4; j++)
        acc[i][j] = __builtin_amdgcn_mfma_f32_16x16x32_bf16(af[i], bfr[j], acc[i][j], 0, 0, 0);
    __syncthreads();
  }

  // epilogue: C/D layout col=lane&15, row=(lane>>4)*4+r
  const int er = (lane >> 4) * 4;
  const int ec = lane & 15;
#pragma unroll
  for (int i = 0; i < 4; i++) {
#pragma unroll
    for (int j = 0; j < 4; j++) {
      long col = tileN + wc + j * 16 + ec;
      float bv = bias ? bias[col] : 0.f;
#pragma unroll
      for (int r = 0; r < 4; r++) {
        long row = tileM + wr + i * 16 + er + r;
        float v = acc[i][j][r] + bv;
        if (OUT_BF16) ((unsigned short*)Cv)[row * (long)N + col] = f2bf(v);
        else          ((float*)Cv)[row * (long)N + col] = v;
      }
    }
  }
}

// ---------------------------------------------------------------------------
// tiny attention: S=4, one block per (b,h); wave i handles query i
// qkv layout: row r=b*4+s, 3072 cols = [q(1024)|k(1024)|v(1024)], head slice h*256
// ---------------------------------------------------------------------------
__global__ __launch_bounds__(256) void k_attn(const unsigned short* __restrict__ qkv,
                                              unsigned short* __restrict__ o) {
  int b = blockIdx.x;
  int h = blockIdx.y;
  int lane = threadIdx.x & 63;
  int qi = threadIdx.x >> 6;
  const unsigned short* base = qkv + (size_t)b * 4 * 3072 + h * HD;
  float qv[4], kv[4][4], vv[4][4];
#pragma unroll
  for (int t = 0; t < 4; t++) {
    int d = lane + t * 64;
    qv[t] = bf2f(base[(size_t)qi * 3072 + d]);
#pragma unroll
    for (int j = 0; j < 4; j++) {
      kv[j][t] = bf2f(base[(size_t)j * 3072 + 1024 + d]);
      vv[j][t] = bf2f(base[(size_t)j * 3072 + 2048 + d]);
    }
  }
  float sc_[4];
#pragma unroll
  for (int j = 0; j < 4; j++) {
    float p = 0.f;
#pragma unroll
    for (int t = 0; t < 4; t++) p += qv[t] * kv[j][t];
    sc_[j] = wsum(p) * (1.0f / 16.0f);   // 1/sqrt(256)
  }
  float mx = fmaxf(fmaxf(sc_[0], sc_[1]), fmaxf(sc_[2], sc_[3]));
  float e[4], den = 0.f;
#pragma unroll
  for (int j = 0; j < 4; j++) { e[j] = expf(sc_[j] - mx); den += e[j]; }
  float inv = 1.0f / den;
  unsigned short* ob = o + (size_t)(b * 4 + qi) * DD + h * HD;
#pragma unroll
  for (int t = 0; t < 4; t++) {
    float ov = 0.f;
#pragma unroll
    for (int j = 0; j < 4; j++) ov += e[j] * inv * vv[j][t];
    ob[lane + t * 64] = f2bf(ov);
  }
}

// ---------------------------------------------------------------------------
// layernorm(gf + attn) then split: s=0 -> oh (l_expmap0), s=1 -> fh (l_expmap0),
// s=2 -> oeu, s=3 -> feu.  One block per row r = b*4+s.
// ---------------------------------------------------------------------------
__global__ __launch_bounds__(256) void k_ln_split(const unsigned short* __restrict__ gf,
    const unsigned short* __restrict__ attn, const float* __restrict__ lnw,
    const float* __restrict__ lnb, float* __restrict__ dout) {
  __shared__ float red[4];
  int r = blockIdx.x;
  int b = r >> 2, s = r & 3;
  size_t base = (size_t)r * DD;
  float x[4], sum = 0.f, sq = 0.f;
#pragma unroll
  for (int k = 0; k < 4; k++) {
    int d = threadIdx.x + k * 256;
    x[k] = bf2f(gf[base + d]) + bf2f(attn[base + d]);
    sum += x[k]; sq += x[k] * x[k];
  }
  sum = block_sum(sum, red);
  sq  = block_sum(sq, red);
  float mu = sum * (1.0f / (float)DD);
  float var = sq * (1.0f / (float)DD) - mu * mu;
  float inv = rsqrtf(var + 1e-5f);
  float y[4], n2 = 0.f;
#pragma unroll
  for (int k = 0; k < 4; k++) {
    int d = threadIdx.x + k * 256;
    y[k] = (x[k] - mu) * inv * lnw[d] + lnb[d];
    n2 += y[k] * y[k];
  }
  float fmul = 1.0f;
  if (s < 2) {                       // l_expmap0
    n2 = block_sum(n2, red);
    float rc = SCF * sqrtf(n2);
    float si = fminf(fmaxf(rc, EPSF), ASINH_MAXF);
    fmul = sinhf(si) / fmaxf(rc, EPSF);
  }
  size_t offs = (s == 0) ? OFF_OH : (s == 1) ? OFF_FH : (s == 2) ? OFF_OEU : OFF_FEU;
  float* outp = dout + offs + (size_t)b * DD;
#pragma unroll
  for (int k = 0; k < 4; k++) {
    int d = threadIdx.x + k * 256;
    outp[d] = y[k] * fmul;
  }
}

// ---------------------------------------------------------------------------
// cone loss: per row b, x = l_expmap0(raw_b), y = yrow_b;
// pen = relu(oxy_angle(x,y) - half_aperture(x)); atomic accumulate.
// accum: [0]=order sum, [1]=family masked sum, [2]=mask count
// ---------------------------------------------------------------------------
__global__ __launch_bounds__(256) void k_oxy(const float* __restrict__ raw,
    const float* __restrict__ yrow, const int* __restrict__ mask,
    float* __restrict__ accum, int use_mask) {
  __shared__ float red[4];
  int b = blockIdx.x;
  size_t base = (size_t)b * DD;
  float sxx = 0.f, sxy = 0.f, syy = 0.f;
#pragma unroll
  for (int k = 0; k < 4; k++) {
    int d = threadIdx.x + k * 256;
    float xv = raw[base + d], yv = yrow[base + d];
    sxx += xv * xv; sxy += xv * yv; syy += yv * yv;
  }
  sxx = block_sum(sxx, red);
  sxy = block_sum(sxy, red);
  syy = block_sum(syy, red);
  if (threadIdx.x == 0) {
    float nraw = sqrtf(sxx);
    float rc = SCF * nraw;
    float si = fminf(fmaxf(rc, EPSF), ASINH_MAXF);
    float f = sinhf(si) / fmaxf(rc, EPSF);       // l_expmap0 scale
    float x2 = f * f * sxx;
    float xy = f * sxy;
    float y2 = syy;
    float nx = f * nraw;                         // |x|
    float xt = sqrtf(1.0f / CURVF + x2);
    float yt = sqrtf(1.0f / CURVF + y2);
    float c_xyl = CURVF * (xy - xt * yt);
    float num = yt + c_xyl * xt;
    float den = sqrtf(fmaxf(c_xyl * c_xyl - 1.0f, EPSF));
    float ai = num / (nx * den + EPSF);
    ai = fminf(fmaxf(ai, -1.0f + EPSF), 1.0f - EPSF);
    float ang = acosf(ai);
    float asi = 0.2f / (nx * SCF + EPSF);        // 2*min_radius
    asi = fminf(fmaxf(asi, -1.0f + EPSF), 1.0f - EPSF);
    float ap = asinf(asi);
    float pen = fmaxf(ang - ap, 0.0f);
    if (use_mask) {
      float m = (float)mask[b];
      atomicAdd(&accum[1], pen * m);
      atomicAdd(&accum[2], m);
    } else {
      atomicAdd(&accum[0], pen);
    }
  }
}

__global__ void k_finalize(const float* __restrict__ accum, float* __restrict__ dout) {
  if (blockIdx.x == 0 && threadIdx.x == 0) {
    float order_loss = accum[0] / (float)BB;
    float cnt = accum[2];
    float fam = (cnt > 0.f) ? accum[1] / fmaxf(cnt, 1.0f) : 0.0f;
    dout[OFF_LOSS] = order_loss + fam;
  }
}

// ---------------------------------------------------------------------------
// MLR precompute: p_p = p_expmap0(mlr_p); a_p = mlr_a*conf; per-c scalars.
// cs[c] = {x2, conf, a_norm, kk, xa}
// ---------------------------------------------------------------------------
__global__ __launch_bounds__(256) void k_mlr_prep(const float* __restrict__ a,
    const float* __restrict__ p, float* __restrict__ p_p, float* __restrict__ a_p,
    float* __restrict__ cs) {
  __shared__ float red[4];
  int c = blockIdx.x;
  size_t base = (size_t)c * DD;
  float sp = 0.f, sa = 0.f, spa = 0.f, pv[4], av[4];
#pragma unroll
  for (int k = 0; k < 4; k++) {
    int d = threadIdx.x + k * 256;
    pv[k] = p[base + d]; av[k] = a[base + d];
    sp += pv[k] * pv[k]; sa += av[k] * av[k]; spa += pv[k] * av[k];
  }
  sp = block_sum(sp, red); sa = block_sum(sa, red); spa = block_sum(spa, red);
  float n = fmaxf(sqrtf(sp), 1e-15f);
  float f = tanhf(SCF * n) / (SCF * n);
  float x2 = f * f * sp;
  float conf = 1.0f - CURVF * x2;
  float a_norm = fabsf(conf) * sqrtf(sa);
  float lam = 2.0f / (1.0f - CURVF * x2);
  float kk = lam * a_norm / SCF;
  float xa = -f * conf * spa;       // (-p_p) . a_p
#pragma unroll
  for (int k = 0; k < 4; k++) {
    int d = threadIdx.x + k * 256;
    p_p[base + d] = pv[k] * f;
    a_p[base + d] = av[k] * conf;
  }
  if (threadIdx.x == 0) {
    cs[c * 5 + 0] = x2; cs[c * 5 + 1] = conf; cs[c * 5 + 2] = a_norm;
    cs[c * 5 + 3] = kk; cs[c * 5 + 4] = xa;
  }
}

// ---------------------------------------------------------------------------
// Fused: hyp_pt = p_project(p_expmap0(l_logmap0(oh)))  [pure per-row scalar s]
// + hyperbolic MLR logits via collapsed mobius algebra.
// One block per b; wave w handles classes [4w, 4w+4).
// ---------------------------------------------------------------------------
__global__ __launch_bounds__(256) void k_mlr_logits(const float* __restrict__ oh,
    const float* __restrict__ p_p, const float* __restrict__ a_p,
    const float* __restrict__ cs, float* __restrict__ logits) {
  __shared__ float row[DD];
  __shared__ float dots[CC][2];
  __shared__ float s_n2;
  int b = blockIdx.x;
  int lane = threadIdx.x & 63, wv = threadIdx.x >> 6;
#pragma unroll
  for (int k = 0; k < 4; k++)
    row[threadIdx.x + k * 256] = oh[(size_t)b * DD + threadIdx.x + k * 256];
  __syncthreads();
  if (wv == 0) {
    float n2p = 0.f;
#pragma unroll
    for (int k = 0; k < 16; k++) { float v = row[lane + 64 * k]; n2p += v * v; }
    n2p = wsum(n2p);
    if (lane == 0) s_n2 = n2p;
  }
#pragma unroll
  for (int ccc = 0; ccc < 4; ccc++) {
    int c = wv * 4 + ccc;
    float dp = 0.f, da = 0.f;
#pragma unroll
    for (int k = 0; k < 16; k++) {
      int d = lane + 64 * k;
      float v = row[d];
      dp += p_p[(size_t)c * DD + d] * v;
      da += a_p[(size_t)c * DD + d] * v;
    }
    dp = wsum(dp); da = wsum(da);
    if (lane == 0) { dots[c][0] = dp; dots[c][1] = da; }
  }
  __syncthreads();
  if (threadIdx.x < CC) {
    int c = threadIdx.x;
    float n2 = s_n2;
    float n1 = sqrtf(n2);
    // l_logmap0 -> p_expmap0 -> p_project collapses to y = s * oh
    float rc = SCF * n1;
    float g = asinhf(rc) / fmaxf(rc, EPSF);
    float nu = fmaxf(n1 * g, 1e-15f);
    float fac = tanhf(SCF * nu) / (SCF * nu);
    float s = g * fac;
    float ny = fmaxf(n1 * s, 1e-15f);
    float maxn = (1.0f - 0.004f) / SCF;
    if (ny > maxn) s *= maxn / ny;
    float y2 = s * s * n2;
    float py = s * dots[c][0];
    float ay = s * dots[c][1];
    float x2 = cs[c * 5 + 0], conf = cs[c * 5 + 1], a_norm = cs[c * 5 + 2];
    float kk = cs[c * 5 + 3], xa = cs[c * 5 + 4];
    float xy = -py;                                  // (-p_p) . y
    float A = 1.f + 2.f * CURVF * xy + CURVF * y2;
    float den0 = 1.f + 2.f * CURVF * xy + CURVF * CURVF * x2 * y2;
    float d = den0 + 1e-5f;
    float num = 2.f * SCF * (A * xa + conf * ay) / d;
    float mob2 = (A * A * x2 + 2.f * A * conf * xy + conf * conf * y2) / (d * d);
    float denl = a_norm * (1.f - CURVF * mob2);
    logits[(size_t)b * CC + c] = kk * asinhf(num / denl);
  }
}

// ---------------------------------------------------------------------------
// Launcher
// ---------------------------------------------------------------------------
extern "C" void kernel_launch(void* const* d_in, const int* in_sizes, int n_in,
                              void* d_out, int out_size, void* d_ws, size_t ws_size,
                              hipStream_t stream) {
  const float* order_hyp  = (const float*)d_in[0];
  const float* family_hyp = (const float*)d_in[1];
  const float* order_euc  = (const float*)d_in[2];
  const float* family_euc = (const float*)d_in[3];
  const float* order      = (const float*)d_in[4];
  const float* family     = (const float*)d_in[5];
  const int*   mask       = (const int*)d_in[6];
  const float* in_proj_w  = (const float*)d_in[7];
  const float* in_proj_b  = (const float*)d_in[8];
  const float* out_proj_w = (const float*)d_in[9];
  const float* out_proj_b = (const float*)d_in[10];
  const float* ln_w       = (const float*)d_in[11];
  const float* ln_b       = (const float*)d_in[12];
  const float* to_w       = (const float*)d_in[13];
  const float* to_b       = (const float*)d_in[14];
  const float* tf_w       = (const float*)d_in[15];
  const float* tf_b       = (const float*)d_in[16];
  const float* mlr_a      = (const float*)d_in[17];
  const float* mlr_p      = (const float*)d_in[18];
  float* dout = (float*)d_out;

  char* w = (char*)d_ws;
  size_t off = 0;
  auto take = [&](size_t n) { char* p = w + off; off += (n + 255) & ~(size_t)255; return p; };
  unsigned short* gf_bf   = (unsigned short*)take((size_t)M1 * DD * 2);        // 33.5 MB
  unsigned short* region2 = (unsigned short*)take((size_t)M1 * 3 * DD * 2);    // 100.7 MB (qkv, reused)
  unsigned short* o_bf    = (unsigned short*)take((size_t)M1 * DD * 2);        // 33.5 MB
  unsigned short* win_bf  = (unsigned short*)take((size_t)3 * DD * DD * 2);
  unsigned short* wout_bf = (unsigned short*)take((size_t)DD * DD * 2);
  unsigned short* tow_bf  = (unsigned short*)take((size_t)DD * TT * 2);
  unsigned short* tfw_bf  = (unsigned short*)take((size_t)DD * TT * 2);
  unsigned short* ord_bf  = (unsigned short*)take((size_t)BB * TT * 2);
  unsigned short* fam_bf  = (unsigned short*)take((size_t)BB * TT * 2);
  float* p_p   = (float*)take((size_t)CC * DD * 4);
  float* a_p   = (float*)take((size_t)CC * DD * 4);
  float* cs    = (float*)take(CC * 5 * 4);
  float* accum = (float*)take(4 * 4);

  // region2 lifetimes: qkv (gemm1 -> attn), then attn_bf / ofeat / ffeat
  unsigned short* qkv     = region2;
  unsigned short* attn_bf = region2;                                  // 33.5 MB
  float* ofeat = (float*)((char*)region2 + 33554432);                 // 16.8 MB
  float* ffeat = (float*)((char*)region2 + 50331648);                 // 16.8 MB

  k_zero<<<1, 64, 0, stream>>>(accum, 4);

  // weight / activation converts to bf16
  k_f2bf<<<(3 * DD * DD + 255) / 256, 256, 0, stream>>>(in_proj_w, win_bf, 3 * DD * DD);
  k_f2bf<<<(DD * DD + 255) / 256, 256, 0, stream>>>(out_proj_w, wout_bf, DD * DD);
  k_f2bf<<<(DD * TT + 255) / 256, 256, 0, stream>>>(to_w, tow_bf, DD * TT);
  k_f2bf<<<(DD * TT + 255) / 256, 256, 0, stream>>>(tf_w, tfw_bf, DD * TT);
  k_f2bf<<<(BB * TT + 255) / 256, 256, 0, stream>>>(order, ord_bf, BB * TT);
  k_f2bf<<<(BB * TT + 255) / 256, 256, 0, stream>>>(family, fam_bf, BB * TT);

  // gf build (p_logmap0 rows + euc rows)
  k_prep_gf<<<BB, 256, 0, stream>>>(order_hyp, family_hyp, order_euc, family_euc, gf_bf);

  // qkv = gf @ in_proj_w^T + b    (16384 x 3072, K=1024)
  k_gemm_bt<1><<<dim3(3 * DD / 128, M1 / 128), 256, 0, stream>>>(
      gf_bf, win_bf, in_proj_b, qkv, M1, 3 * DD, DD);

  // attention (S=4)
  k_attn<<<dim3(BB, HH), 256, 0, stream>>>(qkv, o_bf);

  // attn = o @ out_proj_w^T + b   (16384 x 1024, K=1024) -- overwrites qkv region
  k_gemm_bt<1><<<dim3(DD / 128, M1 / 128), 256, 0, stream>>>(
      o_bf, wout_bf, out_proj_b, attn_bf, M1, DD, DD);

  // layernorm + split + l_expmap0 -> d_out oh/fh/oeu/feu
  k_ln_split<<<M1, 256, 0, stream>>>(gf_bf, attn_bf, ln_w, ln_b, dout);

  // loss-path GEMMs: (4096 x 1024, K=768)
  k_gemm_bt<0><<<dim3(DD / 128, BB / 128), 256, 0, stream>>>(
      ord_bf, tow_bf, to_b, ofeat, BB, DD, TT);
  k_gemm_bt<0><<<dim3(DD / 128, BB / 128), 256, 0, stream>>>(
      fam_bf, tfw_bf, tf_b, ffeat, BB, DD, TT);

  // cone penalties (order vs fh; family vs oh, masked)
  k_oxy<<<BB, 256, 0, stream>>>(ofeat, dout + OFF_FH, nullptr, accum, 0);
  k_oxy<<<BB, 256, 0, stream>>>(ffeat, dout + OFF_OH, mask, accum, 1);
  k_finalize<<<1, 64, 0, stream>>>(accum, dout);

  // MLR logits
  k_mlr_prep<<<CC, 256, 0, stream>>>(mlr_a, mlr_p, p_p, a_p, cs);
  k_mlr_logits<<<BB, 256, 0, stream>>>(dout + OFF_OH, p_p, a_p, cs, dout + OFF_LOGITS);

  (void)in_sizes; (void)n_in; (void)out_size; (void)ws_size;
}

// Round 2
// 648.634 us; speedup vs baseline: 1.0865x; 1.0865x over previous
//
#include <hip/hip_runtime.h>
#include <stdint.h>

// ---------------------------------------------------------------------------
// Problem constants
// ---------------------------------------------------------------------------
#define BB    4096
#define DD    1024
#define TT    768
#define CC    16
#define HH    4
#define SS    4
#define HD    256
#define M1    (BB*SS)     // 16384 rows
#define CURVF 0.05f
#define SCF   0.22360679774997896f   // sqrt(0.05)
#define EPSF  1e-8f
#define ASINH_MAXF 11.090354888959125f  // asinh(2^15)

// d_out element offsets: [logits B*C][loss 1][oh B*D][fh B*D][oeu B*D][feu B*D]
#define OFF_LOGITS 0ull
#define OFF_LOSS   65536ull
#define OFF_OH     65537ull
#define OFF_FH     (65537ull + 4194304ull)
#define OFF_OEU    (65537ull + 2ull*4194304ull)
#define OFF_FEU    (65537ull + 3ull*4194304ull)

typedef __attribute__((ext_vector_type(8))) short bf16x8;
typedef __attribute__((ext_vector_type(4))) float f32x4;

__device__ __forceinline__ float bf2f(unsigned short h) {
  union { unsigned int u; float f; } v; v.u = ((unsigned int)h) << 16; return v.f;
}
__device__ __forceinline__ unsigned short f2bf(float f) {
  union { float f; unsigned int u; } v; v.f = f;
  unsigned int u = v.u;
  return (unsigned short)((u + 0x7FFFu + ((u >> 16) & 1u)) >> 16);
}
__device__ __forceinline__ ushort4 f2bf4(float4 v) {
  ushort4 o; o.x = f2bf(v.x); o.y = f2bf(v.y); o.z = f2bf(v.z); o.w = f2bf(v.w);
  return o;
}
__device__ __forceinline__ float wsum(float v) {
#pragma unroll
  for (int o = 32; o > 0; o >>= 1) v += __shfl_xor(v, o, 64);
  return v;
}
__device__ __forceinline__ float block_sum(float v, float* red) {
  v = wsum(v);
  int lane = threadIdx.x & 63, wv = threadIdx.x >> 6;
  __syncthreads();
  if (lane == 0) red[wv] = v;
  __syncthreads();
  return red[0] + red[1] + red[2] + red[3];
}
__device__ __forceinline__ float artanh_clip(float x) {
  x = fminf(fmaxf(x, -1.0f + 1e-5f), 1.0f - 1e-5f);
  return 0.5f * (log1pf(x) - log1pf(-x));
}

typedef __attribute__((address_space(1))) const void gas_void;
typedef __attribute__((address_space(3))) void las_void;
__device__ __forceinline__ void gld16(void* l, const void* g) {
  __builtin_amdgcn_global_load_lds((gas_void*)g, (las_void*)l, 16, 0, 0);
}

// ---------------------------------------------------------------------------
// merged fp32 -> bf16 convert over 6 segments (float4-wide)
// ---------------------------------------------------------------------------
struct Cvt6 {
  const float4* src[6];
  unsigned short* dst[6];
  unsigned int end4[6];   // cumulative float4 counts
};
__global__ __launch_bounds__(256) void k_cvt6(Cvt6 c, unsigned int total4) {
  unsigned int i = blockIdx.x * 256 + threadIdx.x;
  if (i >= total4) return;
#pragma unroll
  for (int j = 0; j < 6; j++) {
    if (i < c.end4[j]) {
      unsigned int k = i - (j ? c.end4[j - 1] : 0u);
      ((ushort4*)c.dst[j])[k] = f2bf4(c.src[j][k]);
      return;
    }
  }
}

__global__ void k_zero(float* p, int n) {
  int i = blockIdx.x * 64 + threadIdx.x;
  if (i < n) p[i] = 0.f;
}

// ---------------------------------------------------------------------------
// gf = stack([p_logmap0(order_hyp), p_logmap0(family_hyp), order_euc, family_euc])
// one block per b; float4-wide; writes bf16 gf (B*4, D)
// ---------------------------------------------------------------------------
__global__ __launch_bounds__(256) void k_prep_gf(const float* __restrict__ ohyp,
    const float* __restrict__ fhyp, const float* __restrict__ oeuc,
    const float* __restrict__ feuc, unsigned short* __restrict__ gf) {
  __shared__ float red[4];
  int b = blockIdx.x;
  int t = threadIdx.x;
  size_t base4 = (size_t)b * (DD / 4);
  float4 xo = ((const float4*)ohyp)[base4 + t];
  float4 xf = ((const float4*)fhyp)[base4 + t];
  float so = xo.x * xo.x + xo.y * xo.y + xo.z * xo.z + xo.w * xo.w;
  float sf = xf.x * xf.x + xf.y * xf.y + xf.z * xf.z + xf.w * xf.w;
  float no2 = block_sum(so, red);
  float nf2 = block_sum(sf, red);
  float no = fmaxf(sqrtf(no2), 1e-15f);
  float nf = fmaxf(sqrtf(nf2), 1e-15f);
  float fo = artanh_clip(SCF * no) / (no * SCF);
  float ff = artanh_clip(SCF * nf) / (nf * SCF);
  size_t g0 = (size_t)b * 4 * (DD / 4);
  float4 e2 = ((const float4*)oeuc)[base4 + t];
  float4 e3 = ((const float4*)feuc)[base4 + t];
  float4 y0 = {xo.x * fo, xo.y * fo, xo.z * fo, xo.w * fo};
  float4 y1 = {xf.x * ff, xf.y * ff, xf.z * ff, xf.w * ff};
  ((ushort4*)gf)[g0 + t]              = f2bf4(y0);
  ((ushort4*)gf)[g0 + DD / 4 + t]     = f2bf4(y1);
  ((ushort4*)gf)[g0 + 2 * DD / 4 + t] = f2bf4(e2);
  ((ushort4*)gf)[g0 + 3 * DD / 4 + t] = f2bf4(e3);
}

// ---------------------------------------------------------------------------
// bf16 GEMM body, C = A(MxK) * Bm(NxK)^T + bias. 128x128 tile, 4 waves,
// mfma_16x16x32_bf16. LDS XOR-swizzle: physical chunk = logical ^ ((row>>1)&3)
// so ds_read_b128 phases hit all 32 banks (conflict-free) while keeping
// global_load_lds's wave-contiguous destination.
// ---------------------------------------------------------------------------
template <int OUT_BF16>
__device__ __forceinline__ void gemm_body(
    unsigned short* As, unsigned short* Bs,
    const unsigned short* __restrict__ A, const unsigned short* __restrict__ Bm,
    const float* __restrict__ bias, void* __restrict__ Cv,
    int M, int N, int K, int bx, int by) {
  const int tid = threadIdx.x;
  const int lane = tid & 63;
  const int wv = tid >> 6;
  const long tileM = (long)by * 128;
  const long tileN = (long)bx * 128;

  f32x4 acc[4][4];
#pragma unroll
  for (int i = 0; i < 4; i++)
#pragma unroll
    for (int j = 0; j < 4; j++) acc[i][j] = (f32x4){0.f, 0.f, 0.f, 0.f};

  // staging: wave w covers rows [w*16, w*16+16) and +64; swizzled source col
  const int srow = wv * 16 + (lane >> 2);
  const int lc = (lane & 3) ^ ((srow >> 1) & 3);   // logical chunk this lane fetches
  const unsigned short* Ag = A + (tileM + srow) * (long)K + lc * 8;
  const unsigned short* Bg = Bm + (tileN + srow) * (long)K + lc * 8;
  unsigned short* Asl = As + srow * 32 + (lane & 3) * 8;  // wave base + lane*16B
  unsigned short* Bsl = Bs + srow * 32 + (lane & 3) * 8;

  const int fr = lane & 15;                       // fragment row
  const int rkey = (fr >> 1) & 3;                 // read-side swizzle key
  const int fko2 = (((lane >> 4) ^ rkey)) * 8;    // physical chunk offset (elems)
  const int wr = (wv >> 1) * 64;
  const int wc = (wv & 1) * 64;

  for (int k0 = 0; k0 < K; k0 += 32) {
    gld16(Asl, Ag + k0);
    gld16(Asl + 64 * 32, Ag + (long)64 * K + k0);
    gld16(Bsl, Bg + k0);
    gld16(Bsl + 64 * 32, Bg + (long)64 * K + k0);
    __syncthreads();
    bf16x8 af[4], bfr[4];
#pragma unroll
    for (int i = 0; i < 4; i++)
      af[i] = *(const bf16x8*)(As + (wr + i * 16 + fr) * 32 + fko2);
#pragma unroll
    for (int j = 0; j < 4; j++)
      bfr[j] = *(const bf16x8*)(Bs + (wc + j * 16 + fr) * 32 + fko2);
#pragma unroll
    for (int i = 0; i < 4; i++)
#pragma unroll
      for (int j = 0; j < 4; j++)
        acc[i][j] = __builtin_amdgcn_mfma_f32_16x16x32_bf16(af[i], bfr[j], acc[i][j], 0, 0, 0);
    __syncthreads();
  }

  const int er = (lane >> 4) * 4;
  const int ec = lane & 15;
#pragma unroll
  for (int i = 0; i < 4; i++) {
#pragma unroll
    for (int j = 0; j < 4; j++) {
      long col = tileN + wc + j * 16 + ec;
      float bv = bias ? bias[col] : 0.f;
#pragma unroll
      for (int r = 0; r < 4; r++) {
        long row = tileM + wr + i * 16 + er + r;
        float v = acc[i][j][r] + bv;
        if (OUT_BF16) ((unsigned short*)Cv)[row * (long)N + col] = f2bf(v);
        else          ((float*)Cv)[row * (long)N + col] = v;
      }
    }
  }
}

template <int OUT_BF16>
__global__ __launch_bounds__(256) void k_gemm_bt(
    const unsigned short* __restrict__ A, const unsigned short* __restrict__ Bm,
    const float* __restrict__ bias, void* __restrict__ Cv, int M, int N, int K) {
  __shared__ unsigned short As[128 * 32];
  __shared__ unsigned short Bs[128 * 32];
  gemm_body<OUT_BF16>(As, Bs, A, Bm, bias, Cv, M, N, K, blockIdx.x, blockIdx.y);
}

// both loss GEMMs in one dispatch (blockIdx.z selects problem)
__global__ __launch_bounds__(256) void k_gemm_loss(
    const unsigned short* __restrict__ A0, const unsigned short* __restrict__ B0,
    const float* __restrict__ b0, float* __restrict__ C0,
    const unsigned short* __restrict__ A1, const unsigned short* __restrict__ B1,
    const float* __restrict__ b1, float* __restrict__ C1, int M, int N, int K) {
  __shared__ unsigned short As[128 * 32];
  __shared__ unsigned short Bs[128 * 32];
  if (blockIdx.z == 0)
    gemm_body<0>(As, Bs, A0, B0, b0, C0, M, N, K, blockIdx.x, blockIdx.y);
  else
    gemm_body<0>(As, Bs, A1, B1, b1, C1, M, N, K, blockIdx.x, blockIdx.y);
}

// ---------------------------------------------------------------------------
// tiny attention: S=4, one block per (b,h); wave qi handles query qi.
// vectorized: lane covers d = lane*4 .. +3 (ushort4 = 8B loads)
// ---------------------------------------------------------------------------
__global__ __launch_bounds__(256) void k_attn(const unsigned short* __restrict__ qkv,
                                              unsigned short* __restrict__ o) {
  int b = blockIdx.x;
  int h = blockIdx.y;
  int lane = threadIdx.x & 63;
  int qi = threadIdx.x >> 6;
  const unsigned short* base = qkv + (size_t)b * 4 * 3072 + h * HD;
  int d = lane * 4;
  float qv[4], kv[4][4], vv[4][4];
  {
    ushort4 q4 = *(const ushort4*)(base + (size_t)qi * 3072 + d);
    qv[0] = bf2f(q4.x); qv[1] = bf2f(q4.y); qv[2] = bf2f(q4.z); qv[3] = bf2f(q4.w);
  }
#pragma unroll
  for (int j = 0; j < 4; j++) {
    ushort4 k4 = *(const ushort4*)(base + (size_t)j * 3072 + 1024 + d);
    ushort4 v4 = *(const ushort4*)(base + (size_t)j * 3072 + 2048 + d);
    kv[j][0] = bf2f(k4.x); kv[j][1] = bf2f(k4.y); kv[j][2] = bf2f(k4.z); kv[j][3] = bf2f(k4.w);
    vv[j][0] = bf2f(v4.x); vv[j][1] = bf2f(v4.y); vv[j][2] = bf2f(v4.z); vv[j][3] = bf2f(v4.w);
  }
  float sc_[4];
#pragma unroll
  for (int j = 0; j < 4; j++) {
    float p = 0.f;
#pragma unroll
    for (int t = 0; t < 4; t++) p += qv[t] * kv[j][t];
    sc_[j] = wsum(p) * (1.0f / 16.0f);   // 1/sqrt(256)
  }
  float mx = fmaxf(fmaxf(sc_[0], sc_[1]), fmaxf(sc_[2], sc_[3]));
  float e[4], den = 0.f;
#pragma unroll
  for (int j = 0; j < 4; j++) { e[j] = expf(sc_[j] - mx); den += e[j]; }
  float inv = 1.0f / den;
  float4 ov = {0.f, 0.f, 0.f, 0.f};
#pragma unroll
  for (int j = 0; j < 4; j++) {
    float w = e[j] * inv;
    ov.x += w * vv[j][0]; ov.y += w * vv[j][1];
    ov.z += w * vv[j][2]; ov.w += w * vv[j][3];
  }
  *(ushort4*)(o + (size_t)(b * 4 + qi) * DD + h * HD + d) = f2bf4(ov);
}

// ---------------------------------------------------------------------------
// layernorm(gf + attn) then split; s<2 additionally l_expmap0. float4-wide.
// ---------------------------------------------------------------------------
__global__ __launch_bounds__(256) void k_ln_split(const unsigned short* __restrict__ gf,
    const unsigned short* __restrict__ attn, const float* __restrict__ lnw,
    const float* __restrict__ lnb, float* __restrict__ dout) {
  __shared__ float red[4];
  int r = blockIdx.x;
  int b = r >> 2, s = r & 3;
  int t = threadIdx.x;
  size_t base4 = (size_t)r * (DD / 4);
  ushort4 g4 = ((const ushort4*)gf)[base4 + t];
  ushort4 a4 = ((const ushort4*)attn)[base4 + t];
  float x[4] = {bf2f(g4.x) + bf2f(a4.x), bf2f(g4.y) + bf2f(a4.y),
                bf2f(g4.z) + bf2f(a4.z), bf2f(g4.w) + bf2f(a4.w)};
  float sum = x[0] + x[1] + x[2] + x[3];
  float sq = x[0] * x[0] + x[1] * x[1] + x[2] * x[2] + x[3] * x[3];
  sum = block_sum(sum, red);
  sq  = block_sum(sq, red);
  float mu = sum * (1.0f / (float)DD);
  float var = sq * (1.0f / (float)DD) - mu * mu;
  float inv = rsqrtf(var + 1e-5f);
  float4 w4 = ((const float4*)lnw)[t];
  float4 b4 = ((const float4*)lnb)[t];
  float y[4];
  y[0] = (x[0] - mu) * inv * w4.x + b4.x;
  y[1] = (x[1] - mu) * inv * w4.y + b4.y;
  y[2] = (x[2] - mu) * inv * w4.z + b4.z;
  y[3] = (x[3] - mu) * inv * w4.w + b4.w;
  float fmul = 1.0f;
  if (s < 2) {
    float n2 = y[0] * y[0] + y[1] * y[1] + y[2] * y[2] + y[3] * y[3];
    n2 = block_sum(n2, red);
    float rc = SCF * sqrtf(n2);
    float si = fminf(fmaxf(rc, EPSF), ASINH_MAXF);
    fmul = sinhf(si) / fmaxf(rc, EPSF);
  }
  size_t offs = (s == 0) ? OFF_OH : (s == 1) ? OFF_FH : (s == 2) ? OFF_OEU : OFF_FEU;
  float4* outp = (float4*)(dout + offs + (size_t)b * DD);
  float4 o4 = {y[0] * fmul, y[1] * fmul, y[2] * fmul, y[3] * fmul};
  outp[t] = o4;
}

// ---------------------------------------------------------------------------
// cone loss, both branches in one launch (blockIdx.y): per row b,
// x = l_expmap0(raw_b), pen = relu(oxy_angle(x,y) - half_aperture(x)).
// accum: [0]=order sum, [1]=family masked sum, [2]=mask count
// ---------------------------------------------------------------------------
__global__ __launch_bounds__(256) void k_oxy(const float* __restrict__ raw0,
    const float* __restrict__ y0, const float* __restrict__ raw1,
    const float* __restrict__ y1, const int* __restrict__ mask,
    float* __restrict__ accum) {
  __shared__ float red[4];
  int b = blockIdx.x;
  int which = blockIdx.y;
  const float* raw = which ? raw1 : raw0;
  const float* yr  = which ? y1 : y0;
  int t = threadIdx.x;
  size_t base4 = (size_t)b * (DD / 4);
  float4 xv = ((const float4*)raw)[base4 + t];
  float4 yv = ((const float4*)yr)[base4 + t];
  float sxx = xv.x * xv.x + xv.y * xv.y + xv.z * xv.z + xv.w * xv.w;
  float sxy = xv.x * yv.x + xv.y * yv.y + xv.z * yv.z + xv.w * yv.w;
  float syy = yv.x * yv.x + yv.y * yv.y + yv.z * yv.z + yv.w * yv.w;
  sxx = block_sum(sxx, red);
  sxy = block_sum(sxy, red);
  syy = block_sum(syy, red);
  if (threadIdx.x == 0) {
    float nraw = sqrtf(sxx);
    float rc = SCF * nraw;
    float si = fminf(fmaxf(rc, EPSF), ASINH_MAXF);
    float f = sinhf(si) / fmaxf(rc, EPSF);
    float x2 = f * f * sxx;
    float xy = f * sxy;
    float y2 = syy;
    float nx = f * nraw;
    float xt = sqrtf(1.0f / CURVF + x2);
    float yt = sqrtf(1.0f / CURVF + y2);
    float c_xyl = CURVF * (xy - xt * yt);
    float num = yt + c_xyl * xt;
    float den = sqrtf(fmaxf(c_xyl * c_xyl - 1.0f, EPSF));
    float ai = num / (nx * den + EPSF);
    ai = fminf(fmaxf(ai, -1.0f + EPSF), 1.0f - EPSF);
    float ang = acosf(ai);
    float asi = 0.2f / (nx * SCF + EPSF);
    asi = fminf(fmaxf(asi, -1.0f + EPSF), 1.0f - EPSF);
    float ap = asinf(asi);
    float pen = fmaxf(ang - ap, 0.0f);
    if (which) {
      float m = (float)mask[b];
      atomicAdd(&accum[1], pen * m);
      atomicAdd(&accum[2], m);
    } else {
      atomicAdd(&accum[0], pen);
    }
  }
}

__global__ void k_finalize(const float* __restrict__ accum, float* __restrict__ dout) {
  if (blockIdx.x == 0 && threadIdx.x == 0) {
    float order_loss = accum[0] / (float)BB;
    float cnt = accum[2];
    float fam = (cnt > 0.f) ? accum[1] / fmaxf(cnt, 1.0f) : 0.0f;
    dout[OFF_LOSS] = order_loss + fam;
  }
}

// ---------------------------------------------------------------------------
// MLR precompute: cs[c] = {x2, conf, a_norm, kk, xa}
// ---------------------------------------------------------------------------
__global__ __launch_bounds__(256) void k_mlr_prep(const float* __restrict__ a,
    const float* __restrict__ p, float* __restrict__ p_p, float* __restrict__ a_p,
    float* __restrict__ cs) {
  __shared__ float red[4];
  int c = blockIdx.x;
  int t = threadIdx.x;
  size_t base4 = (size_t)c * (DD / 4);
  float4 pv = ((const float4*)p)[base4 + t];
  float4 av = ((const float4*)a)[base4 + t];
  float sp = pv.x * pv.x + pv.y * pv.y + pv.z * pv.z + pv.w * pv.w;
  float sa = av.x * av.x + av.y * av.y + av.z * av.z + av.w * av.w;
  float spa = pv.x * av.x + pv.y * av.y + pv.z * av.z + pv.w * av.w;
  sp = block_sum(sp, red); sa = block_sum(sa, red); spa = block_sum(spa, red);
  float n = fmaxf(sqrtf(sp), 1e-15f);
  float f = tanhf(SCF * n) / (SCF * n);
  float x2 = f * f * sp;
  float conf = 1.0f - CURVF * x2;
  float a_norm = fabsf(conf) * sqrtf(sa);
  float lam = 2.0f / (1.0f - CURVF * x2);
  float kk = lam * a_norm / SCF;
  float xa = -f * conf * spa;
  float4 pp = {pv.x * f, pv.y * f, pv.z * f, pv.w * f};
  float4 ap = {av.x * conf, av.y * conf, av.z * conf, av.w * conf};
  ((float4*)p_p)[base4 + t] = pp;
  ((float4*)a_p)[base4 + t] = ap;
  if (threadIdx.x == 0) {
    cs[c * 5 + 0] = x2; cs[c * 5 + 1] = conf; cs[c * 5 + 2] = a_norm;
    cs[c * 5 + 3] = kk; cs[c * 5 + 4] = xa;
  }
}

// ---------------------------------------------------------------------------
// MLR logits with collapsed mobius algebra; float4-wide dot products.
// ---------------------------------------------------------------------------
__global__ __launch_bounds__(256) void k_mlr_logits(const float* __restrict__ oh,
    const float* __restrict__ p_p, const float* __restrict__ a_p,
    const float* __restrict__ cs, float* __restrict__ logits) {
  __shared__ float row[DD];
  __shared__ float dots[CC][2];
  __shared__ float s_n2;
  int b = blockIdx.x;
  int lane = threadIdx.x & 63, wv = threadIdx.x >> 6;
  ((float4*)row)[threadIdx.x] = ((const float4*)(oh + (size_t)b * DD))[threadIdx.x];
  __syncthreads();
  if (wv == 0) {
    float n2p = 0.f;
#pragma unroll
    for (int k = 0; k < 4; k++) {
      float4 v = ((const float4*)row)[lane + 64 * k];
      n2p += v.x * v.x + v.y * v.y + v.z * v.z + v.w * v.w;
    }
    n2p = wsum(n2p);
    if (lane == 0) s_n2 = n2p;
  }
#pragma unroll
  for (int ccc = 0; ccc < 4; ccc++) {
    int c = wv * 4 + ccc;
    const float4* pp4 = (const float4*)(p_p + (size_t)c * DD);
    const float4* ap4 = (const float4*)(a_p + (size_t)c * DD);
    float dp = 0.f, da = 0.f;
#pragma unroll
    for (int k = 0; k < 4; k++) {
      int d4 = lane + 64 * k;
      float4 v = ((const float4*)row)[d4];
      float4 p4 = pp4[d4];
      float4 a4 = ap4[d4];
      dp += p4.x * v.x + p4.y * v.y + p4.z * v.z + p4.w * v.w;
      da += a4.x * v.x + a4.y * v.y + a4.z * v.z + a4.w * v.w;
    }
    dp = wsum(dp); da = wsum(da);
    if (lane == 0) { dots[c][0] = dp; dots[c][1] = da; }
  }
  __syncthreads();
  if (threadIdx.x < CC) {
    int c = threadIdx.x;
    float n2 = s_n2;
    float n1 = sqrtf(n2);
    float rc = SCF * n1;
    float g = asinhf(rc) / fmaxf(rc, EPSF);
    float nu = fmaxf(n1 * g, 1e-15f);
    float fac = tanhf(SCF * nu) / (SCF * nu);
    float s = g * fac;
    float ny = fmaxf(n1 * s, 1e-15f);
    float maxn = (1.0f - 0.004f) / SCF;
    if (ny > maxn) s *= maxn / ny;
    float y2 = s * s * n2;
    float py = s * dots[c][0];
    float ay = s * dots[c][1];
    float x2 = cs[c * 5 + 0], conf = cs[c * 5 + 1], a_norm = cs[c * 5 + 2];
    float kk = cs[c * 5 + 3], xa = cs[c * 5 + 4];
    float xy = -py;
    float A = 1.f + 2.f * CURVF * xy + CURVF * y2;
    float den0 = 1.f + 2.f * CURVF * xy + CURVF * CURVF * x2 * y2;
    float d = den0 + 1e-5f;
    float num = 2.f * SCF * (A * xa + conf * ay) / d;
    float mob2 = (A * A * x2 + 2.f * A * conf * xy + conf * conf * y2) / (d * d);
    float denl = a_norm * (1.f - CURVF * mob2);
    logits[(size_t)b * CC + c] = kk * asinhf(num / denl);
  }
}

// ---------------------------------------------------------------------------
// Launcher
// ---------------------------------------------------------------------------
extern "C" void kernel_launch(void* const* d_in, const int* in_sizes, int n_in,
                              void* d_out, int out_size, void* d_ws, size_t ws_size,
                              hipStream_t stream) {
  const float* order_hyp  = (const float*)d_in[0];
  const float* family_hyp = (const float*)d_in[1];
  const float* order_euc  = (const float*)d_in[2];
  const float* family_euc = (const float*)d_in[3];
  const float* order      = (const float*)d_in[4];
  const float* family     = (const float*)d_in[5];
  const int*   mask       = (const int*)d_in[6];
  const float* in_proj_w  = (const float*)d_in[7];
  const float* in_proj_b  = (const float*)d_in[8];
  const float* out_proj_w = (const float*)d_in[9];
  const float* out_proj_b = (const float*)d_in[10];
  const float* ln_w       = (const float*)d_in[11];
  const float* ln_b       = (const float*)d_in[12];
  const float* to_w       = (const float*)d_in[13];
  const float* to_b       = (const float*)d_in[14];
  const float* tf_w       = (const float*)d_in[15];
  const float* tf_b       = (const float*)d_in[16];
  const float* mlr_a      = (const float*)d_in[17];
  const float* mlr_p      = (const float*)d_in[18];
  float* dout = (float*)d_out;

  char* w = (char*)d_ws;
  size_t off = 0;
  auto take = [&](size_t n) { char* p = w + off; off += (n + 255) & ~(size_t)255; return p; };
  unsigned short* gf_bf   = (unsigned short*)take((size_t)M1 * DD * 2);
  unsigned short* region2 = (unsigned short*)take((size_t)M1 * 3 * DD * 2);
  unsigned short* o_bf    = (unsigned short*)take((size_t)M1 * DD * 2);
  unsigned short* win_bf  = (unsigned short*)take((size_t)3 * DD * DD * 2);
  unsigned short* wout_bf = (unsigned short*)take((size_t)DD * DD * 2);
  unsigned short* tow_bf  = (unsigned short*)take((size_t)DD * TT * 2);
  unsigned short* tfw_bf  = (unsigned short*)take((size_t)DD * TT * 2);
  unsigned short* ord_bf  = (unsigned short*)take((size_t)BB * TT * 2);
  unsigned short* fam_bf  = (unsigned short*)take((size_t)BB * TT * 2);
  float* p_p   = (float*)take((size_t)CC * DD * 4);
  float* a_p   = (float*)take((size_t)CC * DD * 4);
  float* cs    = (float*)take(CC * 5 * 4);
  float* accum = (float*)take(4 * 4);

  unsigned short* qkv     = region2;
  unsigned short* attn_bf = region2;
  float* ofeat = (float*)((char*)region2 + 33554432);
  float* ffeat = (float*)((char*)region2 + 50331648);

  k_zero<<<1, 64, 0, stream>>>(accum, 4);

  // merged bf16 converts
  Cvt6 cv;
  cv.src[0] = (const float4*)in_proj_w;  cv.dst[0] = win_bf;
  cv.src[1] = (const float4*)out_proj_w; cv.dst[1] = wout_bf;
  cv.src[2] = (const float4*)to_w;       cv.dst[2] = tow_bf;
  cv.src[3] = (const float4*)tf_w;       cv.dst[3] = tfw_bf;
  cv.src[4] = (const float4*)order;      cv.dst[4] = ord_bf;
  cv.src[5] = (const float4*)family;     cv.dst[5] = fam_bf;
  unsigned int n4[6] = {3u * DD * DD / 4, DD * DD / 4, DD * TT / 4, DD * TT / 4,
                        BB * TT / 4, BB * TT / 4};
  unsigned int acc4 = 0;
  for (int j = 0; j < 6; j++) { acc4 += n4[j]; cv.end4[j] = acc4; }
  k_cvt6<<<(acc4 + 255) / 256, 256, 0, stream>>>(cv, acc4);

  k_prep_gf<<<BB, 256, 0, stream>>>(order_hyp, family_hyp, order_euc, family_euc, gf_bf);

  // qkv = gf @ in_proj_w^T + b    (16384 x 3072, K=1024)
  k_gemm_bt<1><<<dim3(3 * DD / 128, M1 / 128), 256, 0, stream>>>(
      gf_bf, win_bf, in_proj_b, qkv, M1, 3 * DD, DD);

  k_attn<<<dim3(BB, HH), 256, 0, stream>>>(qkv, o_bf);

  // attn = o @ out_proj_w^T + b   (16384 x 1024, K=1024)
  k_gemm_bt<1><<<dim3(DD / 128, M1 / 128), 256, 0, stream>>>(
      o_bf, wout_bf, out_proj_b, attn_bf, M1, DD, DD);

  k_ln_split<<<M1, 256, 0, stream>>>(gf_bf, attn_bf, ln_w, ln_b, dout);

  // both loss GEMMs: (4096 x 1024, K=768) x2 in one dispatch
  k_gemm_loss<<<dim3(DD / 128, BB / 128, 2), 256, 0, stream>>>(
      ord_bf, tow_bf, to_b, ofeat, fam_bf, tfw_bf, tf_b, ffeat, BB, DD, TT);

  // cone penalties, both branches in one dispatch
  k_oxy<<<dim3(BB, 2), 256, 0, stream>>>(ofeat, dout + OFF_FH, ffeat, dout + OFF_OH,
                                          mask, accum);
  k_finalize<<<1, 64, 0, stream>>>(accum, dout);

  k_mlr_prep<<<CC, 256, 0, stream>>>(mlr_a, mlr_p, p_p, a_p, cs);
  k_mlr_logits<<<BB, 256, 0, stream>>>(dout + OFF_OH, p_p, a_p, cs, dout + OFF_LOGITS);

  (void)in_sizes; (void)n_in; (void)out_size; (void)ws_size;
}

// Round 3
// 516.553 us; speedup vs baseline: 1.3644x; 1.2557x over previous
//
#include <hip/hip_runtime.h>
#include <stdint.h>

// ---------------------------------------------------------------------------
// Problem constants
// ---------------------------------------------------------------------------
#define BB    4096
#define DD    1024
#define TT    768
#define CC    16
#define HH    4
#define SS    4
#define HD    256
#define M1    (BB*SS)     // 16384 rows
#define CURVF 0.05f
#define SCF   0.22360679774997896f   // sqrt(0.05)
#define EPSF  1e-8f
#define ASINH_MAXF 11.090354888959125f  // asinh(2^15)

// d_out element offsets: [logits B*C][loss 1][oh B*D][fh B*D][oeu B*D][feu B*D]
#define OFF_LOGITS 0ull
#define OFF_LOSS   65536ull
#define OFF_OH     65537ull
#define OFF_FH     (65537ull + 4194304ull)
#define OFF_OEU    (65537ull + 2ull*4194304ull)
#define OFF_FEU    (65537ull + 3ull*4194304ull)

typedef __attribute__((ext_vector_type(8))) short bf16x8;
typedef __attribute__((ext_vector_type(4))) float f32x4;

__device__ __forceinline__ float bf2f(unsigned short h) {
  union { unsigned int u; float f; } v; v.u = ((unsigned int)h) << 16; return v.f;
}
__device__ __forceinline__ unsigned short f2bf(float f) {
  union { float f; unsigned int u; } v; v.f = f;
  unsigned int u = v.u;
  return (unsigned short)((u + 0x7FFFu + ((u >> 16) & 1u)) >> 16);
}
__device__ __forceinline__ ushort4 f2bf4(float4 v) {
  ushort4 o; o.x = f2bf(v.x); o.y = f2bf(v.y); o.z = f2bf(v.z); o.w = f2bf(v.w);
  return o;
}
__device__ __forceinline__ float wsum(float v) {
#pragma unroll
  for (int o = 32; o > 0; o >>= 1) v += __shfl_xor(v, o, 64);
  return v;
}
__device__ __forceinline__ float block_sum(float v, float* red) {
  v = wsum(v);
  int lane = threadIdx.x & 63, wv = threadIdx.x >> 6;
  __syncthreads();
  if (lane == 0) red[wv] = v;
  __syncthreads();
  return red[0] + red[1] + red[2] + red[3];
}
__device__ __forceinline__ float artanh_clip(float x) {
  x = fminf(fmaxf(x, -1.0f + 1e-5f), 1.0f - 1e-5f);
  return 0.5f * (log1pf(x) - log1pf(-x));
}

typedef __attribute__((address_space(1))) const void gas_void;
typedef __attribute__((address_space(3))) void las_void;
__device__ __forceinline__ void gld16(void* l, const void* g) {
  __builtin_amdgcn_global_load_lds((gas_void*)g, (las_void*)l, 16, 0, 0);
}

// ---------------------------------------------------------------------------
// merged fp32 -> bf16 convert over 6 segments (float4-wide)
// ---------------------------------------------------------------------------
struct Cvt6 {
  const float4* src[6];
  unsigned short* dst[6];
  unsigned int end4[6];   // cumulative float4 counts
};
__global__ __launch_bounds__(256) void k_cvt6(Cvt6 c, unsigned int total4) {
  unsigned int i = blockIdx.x * 256 + threadIdx.x;
  if (i >= total4) return;
#pragma unroll
  for (int j = 0; j < 6; j++) {
    if (i < c.end4[j]) {
      unsigned int k = i - (j ? c.end4[j - 1] : 0u);
      ((ushort4*)c.dst[j])[k] = f2bf4(c.src[j][k]);
      return;
    }
  }
}

// ---------------------------------------------------------------------------
// gf = stack([p_logmap0(order_hyp), p_logmap0(family_hyp), order_euc, family_euc])
// ---------------------------------------------------------------------------
__global__ __launch_bounds__(256) void k_prep_gf(const float* __restrict__ ohyp,
    const float* __restrict__ fhyp, const float* __restrict__ oeuc,
    const float* __restrict__ feuc, unsigned short* __restrict__ gf) {
  __shared__ float red[4];
  int b = blockIdx.x;
  int t = threadIdx.x;
  size_t base4 = (size_t)b * (DD / 4);
  float4 xo = ((const float4*)ohyp)[base4 + t];
  float4 xf = ((const float4*)fhyp)[base4 + t];
  float so = xo.x * xo.x + xo.y * xo.y + xo.z * xo.z + xo.w * xo.w;
  float sf = xf.x * xf.x + xf.y * xf.y + xf.z * xf.z + xf.w * xf.w;
  float no2 = block_sum(so, red);
  float nf2 = block_sum(sf, red);
  float no = fmaxf(sqrtf(no2), 1e-15f);
  float nf = fmaxf(sqrtf(nf2), 1e-15f);
  float fo = artanh_clip(SCF * no) / (no * SCF);
  float ff = artanh_clip(SCF * nf) / (nf * SCF);
  size_t g0 = (size_t)b * 4 * (DD / 4);
  float4 e2 = ((const float4*)oeuc)[base4 + t];
  float4 e3 = ((const float4*)feuc)[base4 + t];
  float4 y0 = {xo.x * fo, xo.y * fo, xo.z * fo, xo.w * fo};
  float4 y1 = {xf.x * ff, xf.y * ff, xf.z * ff, xf.w * ff};
  ((ushort4*)gf)[g0 + t]              = f2bf4(y0);
  ((ushort4*)gf)[g0 + DD / 4 + t]     = f2bf4(y1);
  ((ushort4*)gf)[g0 + 2 * DD / 4 + t] = f2bf4(e2);
  ((ushort4*)gf)[g0 + 3 * DD / 4 + t] = f2bf4(e3);
}

// ---------------------------------------------------------------------------
// bf16 GEMM body, C = A(MxK) * Bm(NxK)^T + bias. 128x128 tile, 4 waves,
// mfma_16x16x32_bf16, XOR bank swizzle (conflict-free, verified R2: 0 conflicts)
// ---------------------------------------------------------------------------
template <int OUT_BF16>
__device__ __forceinline__ void gemm_body(
    unsigned short* As, unsigned short* Bs,
    const unsigned short* __restrict__ A, const unsigned short* __restrict__ Bm,
    const float* __restrict__ bias, void* __restrict__ Cv,
    int M, int N, int K, int bx, int by) {
  const int tid = threadIdx.x;
  const int lane = tid & 63;
  const int wv = tid >> 6;
  const long tileM = (long)by * 128;
  const long tileN = (long)bx * 128;

  f32x4 acc[4][4];
#pragma unroll
  for (int i = 0; i < 4; i++)
#pragma unroll
    for (int j = 0; j < 4; j++) acc[i][j] = (f32x4){0.f, 0.f, 0.f, 0.f};

  const int srow = wv * 16 + (lane >> 2);
  const int lc = (lane & 3) ^ ((srow >> 1) & 3);
  const unsigned short* Ag = A + (tileM + srow) * (long)K + lc * 8;
  const unsigned short* Bg = Bm + (tileN + srow) * (long)K + lc * 8;
  unsigned short* Asl = As + srow * 32 + (lane & 3) * 8;
  unsigned short* Bsl = Bs + srow * 32 + (lane & 3) * 8;

  const int fr = lane & 15;
  const int rkey = (fr >> 1) & 3;
  const int fko2 = (((lane >> 4) ^ rkey)) * 8;
  const int wr = (wv >> 1) * 64;
  const int wc = (wv & 1) * 64;

  for (int k0 = 0; k0 < K; k0 += 32) {
    gld16(Asl, Ag + k0);
    gld16(Asl + 64 * 32, Ag + (long)64 * K + k0);
    gld16(Bsl, Bg + k0);
    gld16(Bsl + 64 * 32, Bg + (long)64 * K + k0);
    __syncthreads();
    bf16x8 af[4], bfr[4];
#pragma unroll
    for (int i = 0; i < 4; i++)
      af[i] = *(const bf16x8*)(As + (wr + i * 16 + fr) * 32 + fko2);
#pragma unroll
    for (int j = 0; j < 4; j++)
      bfr[j] = *(const bf16x8*)(Bs + (wc + j * 16 + fr) * 32 + fko2);
#pragma unroll
    for (int i = 0; i < 4; i++)
#pragma unroll
      for (int j = 0; j < 4; j++)
        acc[i][j] = __builtin_amdgcn_mfma_f32_16x16x32_bf16(af[i], bfr[j], acc[i][j], 0, 0, 0);
    __syncthreads();
  }

  const int er = (lane >> 4) * 4;
  const int ec = lane & 15;
#pragma unroll
  for (int i = 0; i < 4; i++) {
#pragma unroll
    for (int j = 0; j < 4; j++) {
      long col = tileN + wc + j * 16 + ec;
      float bv = bias ? bias[col] : 0.f;
#pragma unroll
      for (int r = 0; r < 4; r++) {
        long row = tileM + wr + i * 16 + er + r;
        float v = acc[i][j][r] + bv;
        if (OUT_BF16) ((unsigned short*)Cv)[row * (long)N + col] = f2bf(v);
        else          ((float*)Cv)[row * (long)N + col] = v;
      }
    }
  }
}

template <int OUT_BF16>
__global__ __launch_bounds__(256) void k_gemm_bt(
    const unsigned short* __restrict__ A, const unsigned short* __restrict__ Bm,
    const float* __restrict__ bias, void* __restrict__ Cv, int M, int N, int K) {
  __shared__ unsigned short As[128 * 32];
  __shared__ unsigned short Bs[128 * 32];
  gemm_body<OUT_BF16>(As, Bs, A, Bm, bias, Cv, M, N, K, blockIdx.x, blockIdx.y);
}

__global__ __launch_bounds__(256) void k_gemm_loss(
    const unsigned short* __restrict__ A0, const unsigned short* __restrict__ B0,
    const float* __restrict__ b0, float* __restrict__ C0,
    const unsigned short* __restrict__ A1, const unsigned short* __restrict__ B1,
    const float* __restrict__ b1, float* __restrict__ C1, int M, int N, int K) {
  __shared__ unsigned short As[128 * 32];
  __shared__ unsigned short Bs[128 * 32];
  if (blockIdx.z == 0)
    gemm_body<0>(As, Bs, A0, B0, b0, C0, M, N, K, blockIdx.x, blockIdx.y);
  else
    gemm_body<0>(As, Bs, A1, B1, b1, C1, M, N, K, blockIdx.x, blockIdx.y);
}

// ---------------------------------------------------------------------------
// tiny attention: S=4, one block per (b,h); wave qi handles query qi.
// ---------------------------------------------------------------------------
__global__ __launch_bounds__(256) void k_attn(const unsigned short* __restrict__ qkv,
                                              unsigned short* __restrict__ o) {
  int b = blockIdx.x;
  int h = blockIdx.y;
  int lane = threadIdx.x & 63;
  int qi = threadIdx.x >> 6;
  const unsigned short* base = qkv + (size_t)b * 4 * 3072 + h * HD;
  int d = lane * 4;
  float qv[4], kv[4][4], vv[4][4];
  {
    ushort4 q4 = *(const ushort4*)(base + (size_t)qi * 3072 + d);
    qv[0] = bf2f(q4.x); qv[1] = bf2f(q4.y); qv[2] = bf2f(q4.z); qv[3] = bf2f(q4.w);
  }
#pragma unroll
  for (int j = 0; j < 4; j++) {
    ushort4 k4 = *(const ushort4*)(base + (size_t)j * 3072 + 1024 + d);
    ushort4 v4 = *(const ushort4*)(base + (size_t)j * 3072 + 2048 + d);
    kv[j][0] = bf2f(k4.x); kv[j][1] = bf2f(k4.y); kv[j][2] = bf2f(k4.z); kv[j][3] = bf2f(k4.w);
    vv[j][0] = bf2f(v4.x); vv[j][1] = bf2f(v4.y); vv[j][2] = bf2f(v4.z); vv[j][3] = bf2f(v4.w);
  }
  float sc_[4];
#pragma unroll
  for (int j = 0; j < 4; j++) {
    float p = 0.f;
#pragma unroll
    for (int t = 0; t < 4; t++) p += qv[t] * kv[j][t];
    sc_[j] = wsum(p) * (1.0f / 16.0f);
  }
  float mx = fmaxf(fmaxf(sc_[0], sc_[1]), fmaxf(sc_[2], sc_[3]));
  float e[4], den = 0.f;
#pragma unroll
  for (int j = 0; j < 4; j++) { e[j] = expf(sc_[j] - mx); den += e[j]; }
  float inv = 1.0f / den;
  float4 ov = {0.f, 0.f, 0.f, 0.f};
#pragma unroll
  for (int j = 0; j < 4; j++) {
    float w = e[j] * inv;
    ov.x += w * vv[j][0]; ov.y += w * vv[j][1];
    ov.z += w * vv[j][2]; ov.w += w * vv[j][3];
  }
  *(ushort4*)(o + (size_t)(b * 4 + qi) * DD + h * HD + d) = f2bf4(ov);
}

// ---------------------------------------------------------------------------
// layernorm(gf + attn) then split; s<2 additionally l_expmap0.
// ---------------------------------------------------------------------------
__global__ __launch_bounds__(256) void k_ln_split(const unsigned short* __restrict__ gf,
    const unsigned short* __restrict__ attn, const float* __restrict__ lnw,
    const float* __restrict__ lnb, float* __restrict__ dout) {
  __shared__ float red[4];
  int r = blockIdx.x;
  int b = r >> 2, s = r & 3;
  int t = threadIdx.x;
  size_t base4 = (size_t)r * (DD / 4);
  ushort4 g4 = ((const ushort4*)gf)[base4 + t];
  ushort4 a4 = ((const ushort4*)attn)[base4 + t];
  float x[4] = {bf2f(g4.x) + bf2f(a4.x), bf2f(g4.y) + bf2f(a4.y),
                bf2f(g4.z) + bf2f(a4.z), bf2f(g4.w) + bf2f(a4.w)};
  float sum = x[0] + x[1] + x[2] + x[3];
  float sq = x[0] * x[0] + x[1] * x[1] + x[2] * x[2] + x[3] * x[3];
  sum = block_sum(sum, red);
  sq  = block_sum(sq, red);
  float mu = sum * (1.0f / (float)DD);
  float var = sq * (1.0f / (float)DD) - mu * mu;
  float inv = rsqrtf(var + 1e-5f);
  float4 w4 = ((const float4*)lnw)[t];
  float4 b4 = ((const float4*)lnb)[t];
  float y[4];
  y[0] = (x[0] - mu) * inv * w4.x + b4.x;
  y[1] = (x[1] - mu) * inv * w4.y + b4.y;
  y[2] = (x[2] - mu) * inv * w4.z + b4.z;
  y[3] = (x[3] - mu) * inv * w4.w + b4.w;
  float fmul = 1.0f;
  if (s < 2) {
    float n2 = y[0] * y[0] + y[1] * y[1] + y[2] * y[2] + y[3] * y[3];
    n2 = block_sum(n2, red);
    float rc = SCF * sqrtf(n2);
    float si = fminf(fmaxf(rc, EPSF), ASINH_MAXF);
    fmul = sinhf(si) / fmaxf(rc, EPSF);
  }
  size_t offs = (s == 0) ? OFF_OH : (s == 1) ? OFF_FH : (s == 2) ? OFF_OEU : OFF_FEU;
  float4* outp = (float4*)(dout + offs + (size_t)b * DD);
  float4 o4 = {y[0] * fmul, y[1] * fmul, y[2] * fmul, y[3] * fmul};
  outp[t] = o4;
}

// ---------------------------------------------------------------------------
// cone loss: per row b, pen -> pens[which*BB + b]. NO atomics (R2 post-mortem:
// 12288 same-line atomicAdds serialized at ~13ns each = 161us).
// dout reads are 4B-aligned only -> coalesced dword loads.
// ---------------------------------------------------------------------------
__global__ __launch_bounds__(256) void k_oxy(const float* __restrict__ raw0,
    const float* __restrict__ y0, const float* __restrict__ raw1,
    const float* __restrict__ y1, float* __restrict__ pens) {
  __shared__ float red[4];
  int b = blockIdx.x;
  int which = blockIdx.y;
  const float* raw = which ? raw1 : raw0;
  const float* yr  = which ? y1 : y0;
  size_t base = (size_t)b * DD;
  float sxx = 0.f, sxy = 0.f, syy = 0.f;
#pragma unroll
  for (int k = 0; k < 4; k++) {
    int d = threadIdx.x + 256 * k;
    float xv = raw[base + d];
    float yv = yr[base + d];
    sxx += xv * xv; sxy += xv * yv; syy += yv * yv;
  }
  sxx = block_sum(sxx, red);
  sxy = block_sum(sxy, red);
  syy = block_sum(syy, red);
  if (threadIdx.x == 0) {
    float nraw = sqrtf(sxx);
    float rc = SCF * nraw;
    float si = fminf(fmaxf(rc, EPSF), ASINH_MAXF);
    float f = sinhf(si) / fmaxf(rc, EPSF);
    float x2 = f * f * sxx;
    float xy = f * sxy;
    float y2 = syy;
    float nx = f * nraw;
    float xt = sqrtf(1.0f / CURVF + x2);
    float yt = sqrtf(1.0f / CURVF + y2);
    float c_xyl = CURVF * (xy - xt * yt);
    float num = yt + c_xyl * xt;
    float den = sqrtf(fmaxf(c_xyl * c_xyl - 1.0f, EPSF));
    float ai = num / (nx * den + EPSF);
    ai = fminf(fmaxf(ai, -1.0f + EPSF), 1.0f - EPSF);
    float ang = acosf(ai);
    float asi = 0.2f / (nx * SCF + EPSF);
    asi = fminf(fmaxf(asi, -1.0f + EPSF), 1.0f - EPSF);
    float ap = asinf(asi);
    pens[(size_t)which * BB + b] = fmaxf(ang - ap, 0.0f);
  }
}

// single-block reduction of pens + mask -> loss scalar
__global__ __launch_bounds__(256) void k_finalize_loss(const float* __restrict__ pens,
    const int* __restrict__ mask, float* __restrict__ dout) {
  __shared__ float red[4];
  float s0 = 0.f, s1 = 0.f, cnt = 0.f;
  for (int i = threadIdx.x; i < BB; i += 256) {
    s0 += pens[i];
    float m = (float)mask[i];
    s1 += pens[BB + i] * m;
    cnt += m;
  }
  s0 = block_sum(s0, red);
  s1 = block_sum(s1, red);
  cnt = block_sum(cnt, red);
  if (threadIdx.x == 0) {
    float order_loss = s0 / (float)BB;
    float fam = (cnt > 0.f) ? s1 / fmaxf(cnt, 1.0f) : 0.0f;
    dout[OFF_LOSS] = order_loss + fam;
  }
}

// ---------------------------------------------------------------------------
// MLR precompute: cs[c] = {x2, conf, a_norm, kk, xa}
// ---------------------------------------------------------------------------
__global__ __launch_bounds__(256) void k_mlr_prep(const float* __restrict__ a,
    const float* __restrict__ p, float* __restrict__ p_p, float* __restrict__ a_p,
    float* __restrict__ cs) {
  __shared__ float red[4];
  int c = blockIdx.x;
  int t = threadIdx.x;
  size_t base4 = (size_t)c * (DD / 4);
  float4 pv = ((const float4*)p)[base4 + t];
  float4 av = ((const float4*)a)[base4 + t];
  float sp = pv.x * pv.x + pv.y * pv.y + pv.z * pv.z + pv.w * pv.w;
  float sa = av.x * av.x + av.y * av.y + av.z * av.z + av.w * av.w;
  float spa = pv.x * av.x + pv.y * av.y + pv.z * av.z + pv.w * av.w;
  sp = block_sum(sp, red); sa = block_sum(sa, red); spa = block_sum(spa, red);
  float n = fmaxf(sqrtf(sp), 1e-15f);
  float f = tanhf(SCF * n) / (SCF * n);
  float x2 = f * f * sp;
  float conf = 1.0f - CURVF * x2;
  float a_norm = fabsf(conf) * sqrtf(sa);
  float lam = 2.0f / (1.0f - CURVF * x2);
  float kk = lam * a_norm / SCF;
  float xa = -f * conf * spa;
  float4 pp = {pv.x * f, pv.y * f, pv.z * f, pv.w * f};
  float4 ap = {av.x * conf, av.y * conf, av.z * conf, av.w * conf};
  ((float4*)p_p)[base4 + t] = pp;
  ((float4*)a_p)[base4 + t] = ap;
  if (threadIdx.x == 0) {
    cs[c * 5 + 0] = x2; cs[c * 5 + 1] = conf; cs[c * 5 + 2] = a_norm;
    cs[c * 5 + 3] = kk; cs[c * 5 + 4] = xa;
  }
}

// ---------------------------------------------------------------------------
// MLR logits. oh read is 4B-aligned only -> coalesced dword loads into LDS.
// ---------------------------------------------------------------------------
__global__ __launch_bounds__(256) void k_mlr_logits(const float* __restrict__ oh,
    const float* __restrict__ p_p, const float* __restrict__ a_p,
    const float* __restrict__ cs, float* __restrict__ logits) {
  __shared__ float row[DD];
  __shared__ float dots[CC][2];
  __shared__ float s_n2;
  int b = blockIdx.x;
  int lane = threadIdx.x & 63, wv = threadIdx.x >> 6;
  const float* src = oh + (size_t)b * DD;
#pragma unroll
  for (int k = 0; k < 4; k++)
    row[threadIdx.x + 256 * k] = src[threadIdx.x + 256 * k];
  __syncthreads();
  if (wv == 0) {
    float n2p = 0.f;
#pragma unroll
    for (int k = 0; k < 4; k++) {
      float4 v = ((const float4*)row)[lane + 64 * k];
      n2p += v.x * v.x + v.y * v.y + v.z * v.z + v.w * v.w;
    }
    n2p = wsum(n2p);
    if (lane == 0) s_n2 = n2p;
  }
#pragma unroll
  for (int ccc = 0; ccc < 4; ccc++) {
    int c = wv * 4 + ccc;
    const float4* pp4 = (const float4*)(p_p + (size_t)c * DD);
    const float4* ap4 = (const float4*)(a_p + (size_t)c * DD);
    float dp = 0.f, da = 0.f;
#pragma unroll
    for (int k = 0; k < 4; k++) {
      int d4 = lane + 64 * k;
      float4 v = ((const float4*)row)[d4];
      float4 p4 = pp4[d4];
      float4 a4 = ap4[d4];
      dp += p4.x * v.x + p4.y * v.y + p4.z * v.z + p4.w * v.w;
      da += a4.x * v.x + a4.y * v.y + a4.z * v.z + a4.w * v.w;
    }
    dp = wsum(dp); da = wsum(da);
    if (lane == 0) { dots[c][0] = dp; dots[c][1] = da; }
  }
  __syncthreads();
  if (threadIdx.x < CC) {
    int c = threadIdx.x;
    float n2 = s_n2;
    float n1 = sqrtf(n2);
    float rc = SCF * n1;
    float g = asinhf(rc) / fmaxf(rc, EPSF);
    float nu = fmaxf(n1 * g, 1e-15f);
    float fac = tanhf(SCF * nu) / (SCF * nu);
    float s = g * fac;
    float ny = fmaxf(n1 * s, 1e-15f);
    float maxn = (1.0f - 0.004f) / SCF;
    if (ny > maxn) s *= maxn / ny;
    float y2 = s * s * n2;
    float py = s * dots[c][0];
    float ay = s * dots[c][1];
    float x2 = cs[c * 5 + 0], conf = cs[c * 5 + 1], a_norm = cs[c * 5 + 2];
    float kk = cs[c * 5 + 3], xa = cs[c * 5 + 4];
    float xy = -py;
    float A = 1.f + 2.f * CURVF * xy + CURVF * y2;
    float den0 = 1.f + 2.f * CURVF * xy + CURVF * CURVF * x2 * y2;
    float d = den0 + 1e-5f;
    float num = 2.f * SCF * (A * xa + conf * ay) / d;
    float mob2 = (A * A * x2 + 2.f * A * conf * xy + conf * conf * y2) / (d * d);
    float denl = a_norm * (1.f - CURVF * mob2);
    logits[(size_t)b * CC + c] = kk * asinhf(num / denl);
  }
}

// ---------------------------------------------------------------------------
// Launcher
// ---------------------------------------------------------------------------
extern "C" void kernel_launch(void* const* d_in, const int* in_sizes, int n_in,
                              void* d_out, int out_size, void* d_ws, size_t ws_size,
                              hipStream_t stream) {
  const float* order_hyp  = (const float*)d_in[0];
  const float* family_hyp = (const float*)d_in[1];
  const float* order_euc  = (const float*)d_in[2];
  const float* family_euc = (const float*)d_in[3];
  const float* order      = (const float*)d_in[4];
  const float* family     = (const float*)d_in[5];
  const int*   mask       = (const int*)d_in[6];
  const float* in_proj_w  = (const float*)d_in[7];
  const float* in_proj_b  = (const float*)d_in[8];
  const float* out_proj_w = (const float*)d_in[9];
  const float* out_proj_b = (const float*)d_in[10];
  const float* ln_w       = (const float*)d_in[11];
  const float* ln_b       = (const float*)d_in[12];
  const float* to_w       = (const float*)d_in[13];
  const float* to_b       = (const float*)d_in[14];
  const float* tf_w       = (const float*)d_in[15];
  const float* tf_b       = (const float*)d_in[16];
  const float* mlr_a      = (const float*)d_in[17];
  const float* mlr_p      = (const float*)d_in[18];
  float* dout = (float*)d_out;

  char* w = (char*)d_ws;
  size_t off = 0;
  auto take = [&](size_t n) { char* p = w + off; off += (n + 255) & ~(size_t)255; return p; };
  unsigned short* gf_bf   = (unsigned short*)take((size_t)M1 * DD * 2);
  unsigned short* region2 = (unsigned short*)take((size_t)M1 * 3 * DD * 2);
  unsigned short* o_bf    = (unsigned short*)take((size_t)M1 * DD * 2);
  unsigned short* win_bf  = (unsigned short*)take((size_t)3 * DD * DD * 2);
  unsigned short* wout_bf = (unsigned short*)take((size_t)DD * DD * 2);
  unsigned short* tow_bf  = (unsigned short*)take((size_t)DD * TT * 2);
  unsigned short* tfw_bf  = (unsigned short*)take((size_t)DD * TT * 2);
  unsigned short* ord_bf  = (unsigned short*)take((size_t)BB * TT * 2);
  unsigned short* fam_bf  = (unsigned short*)take((size_t)BB * TT * 2);
  float* p_p   = (float*)take((size_t)CC * DD * 4);
  float* a_p   = (float*)take((size_t)CC * DD * 4);
  float* cs    = (float*)take(CC * 5 * 4);
  float* pens  = (float*)take((size_t)2 * BB * 4);

  unsigned short* qkv     = region2;
  unsigned short* attn_bf = region2;
  float* ofeat = (float*)((char*)region2 + 33554432);
  float* ffeat = (float*)((char*)region2 + 50331648);

  // merged bf16 converts
  Cvt6 cv;
  cv.src[0] = (const float4*)in_proj_w;  cv.dst[0] = win_bf;
  cv.src[1] = (const float4*)out_proj_w; cv.dst[1] = wout_bf;
  cv.src[2] = (const float4*)to_w;       cv.dst[2] = tow_bf;
  cv.src[3] = (const float4*)tf_w;       cv.dst[3] = tfw_bf;
  cv.src[4] = (const float4*)order;      cv.dst[4] = ord_bf;
  cv.src[5] = (const float4*)family;     cv.dst[5] = fam_bf;
  unsigned int n4[6] = {3u * DD * DD / 4, DD * DD / 4, DD * TT / 4, DD * TT / 4,
                        BB * TT / 4, BB * TT / 4};
  unsigned int acc4 = 0;
  for (int j = 0; j < 6; j++) { acc4 += n4[j]; cv.end4[j] = acc4; }
  k_cvt6<<<(acc4 + 255) / 256, 256, 0, stream>>>(cv, acc4);

  k_prep_gf<<<BB, 256, 0, stream>>>(order_hyp, family_hyp, order_euc, family_euc, gf_bf);

  // qkv = gf @ in_proj_w^T + b    (16384 x 3072, K=1024)
  k_gemm_bt<1><<<dim3(3 * DD / 128, M1 / 128), 256, 0, stream>>>(
      gf_bf, win_bf, in_proj_b, qkv, M1, 3 * DD, DD);

  k_attn<<<dim3(BB, HH), 256, 0, stream>>>(qkv, o_bf);

  // attn = o @ out_proj_w^T + b   (16384 x 1024, K=1024)
  k_gemm_bt<1><<<dim3(DD / 128, M1 / 128), 256, 0, stream>>>(
      o_bf, wout_bf, out_proj_b, attn_bf, M1, DD, DD);

  k_ln_split<<<M1, 256, 0, stream>>>(gf_bf, attn_bf, ln_w, ln_b, dout);

  // both loss GEMMs: (4096 x 1024, K=768) x2 in one dispatch
  k_gemm_loss<<<dim3(DD / 128, BB / 128, 2), 256, 0, stream>>>(
      ord_bf, tow_bf, to_b, ofeat, fam_bf, tfw_bf, tf_b, ffeat, BB, DD, TT);

  // cone penalties -> per-block partials (no atomics), then tiny reduce
  k_oxy<<<dim3(BB, 2), 256, 0, stream>>>(ofeat, dout + OFF_FH, ffeat, dout + OFF_OH, pens);
  k_finalize_loss<<<1, 256, 0, stream>>>(pens, mask, dout);

  k_mlr_prep<<<CC, 256, 0, stream>>>(mlr_a, mlr_p, p_p, a_p, cs);
  k_mlr_logits<<<BB, 256, 0, stream>>>(dout + OFF_OH, p_p, a_p, cs, dout + OFF_LOGITS);

  (void)in_sizes; (void)n_in; (void)out_size; (void)ws_size;
}